// Round 6
// baseline (185.906 us; speedup 1.0000x reference)
//
#include <hip/hip_runtime.h>
#include <math.h>

#define NUM_LEVELS 5
#define NUM_CLASSES 80
#define TOPK 1000
#define CAND_CAP 4096
#define NBINS 256
#define FLOORV 0.25f
#define BIN_SCALE (256.0f / 0.75f)
#define ELEMS_PER_BLOCK 8192  // 256 threads * 32 elems (4 iters * 8)

struct LevelParams {
    const float* cls[NUM_LEVELS];
    const float* box[NUM_LEVELS];
    const float* pss[NUM_LEVELS];
    int blk_start[NUM_LEVELS + 1];
};

__device__ __forceinline__ float sigf(float x) {
    return 1.0f / (1.0f + __expf(-x));  // selection only; error << bin margin
}

// Step-rounded f32 sigmoid, numpy scalar semantics:
//   e = RN32(exp(-x))   [exp correctly rounded via f64]
//   d = RN32(1 + e)
//   s = RN32(1 / d)
__device__ __forceinline__ float np_sigmoid_f32(float x) {
    float e32 = (float)exp(-(double)x);          // CR f32 exp (double-rounding ~1e-9 risk)
    float d = __fadd_rn(1.0f, e32);
    return __fdiv_rn(1.0f, d);
}

__global__ __launch_bounds__(256) void k_hist(LevelParams P, unsigned* hist) {
    __shared__ unsigned lh[NBINS];
    for (int i = threadIdx.x; i < NBINS; i += 256) lh[i] = 0;
    __syncthreads();

    int lev = 0;
    while ((int)blockIdx.x >= P.blk_start[lev + 1]) ++lev;
    const float* __restrict__ cls = P.cls[lev];
    const float* __restrict__ pss = P.pss[lev];
    const int base = (blockIdx.x - P.blk_start[lev]) * ELEMS_PER_BLOCK;

#pragma unroll
    for (int it = 0; it < 4; ++it) {
        int e = base + (it * 256 + (int)threadIdx.x) * 8;
        int anchor = e / NUM_CLASSES;  // 8-chunk never crosses a row (80 % 8 == 0)
        float sp = sigf(pss[anchor]);
        float4 c0 = *(const float4*)(cls + e);
        float4 c1 = *(const float4*)(cls + e + 4);
        float cs[8] = {c0.x, c0.y, c0.z, c0.w, c1.x, c1.y, c1.z, c1.w};
#pragma unroll
        for (int j = 0; j < 8; ++j) {
            float s = sp * sigf(cs[j]);
            if (s >= FLOORV) {
                int b = (int)((s - FLOORV) * BIN_SCALE);
                if (b > NBINS - 1) b = NBINS - 1;
                atomicAdd(&lh[b], 1u);
            }
        }
    }
    __syncthreads();
    for (int i = threadIdx.x; i < NBINS; i += 256) {
        unsigned v = lh[i];
        if (v) atomicAdd(&hist[lev * NBINS + i], v);
    }
}

__global__ void k_cutoff(const unsigned* hist, int* cutoff) {
    int lev = blockIdx.x;
    if (threadIdx.x == 0) {
        long cum = 0;
        int b = NBINS - 1;
        for (; b >= 0; --b) {
            cum += hist[lev * NBINS + b];
            if (cum >= TOPK) break;
        }
        int sel = (b <= 0) ? 0 : (b - 1);  // one margin bin below the crossing bin
        cutoff[lev] = sel;
    }
}

__global__ __launch_bounds__(256) void k_compact(LevelParams P, const int* cutoff,
                                                 int* count, int* cand) {
    int lev = 0;
    while ((int)blockIdx.x >= P.blk_start[lev + 1]) ++lev;
    const float* __restrict__ cls = P.cls[lev];
    const float* __restrict__ pss = P.pss[lev];
    const int base = (blockIdx.x - P.blk_start[lev]) * ELEMS_PER_BLOCK;
    const int csel = cutoff[lev];

#pragma unroll
    for (int it = 0; it < 4; ++it) {
        int e = base + (it * 256 + (int)threadIdx.x) * 8;
        int anchor = e / NUM_CLASSES;
        float sp = sigf(pss[anchor]);
        float4 c0 = *(const float4*)(cls + e);
        float4 c1 = *(const float4*)(cls + e + 4);
        float cs[8] = {c0.x, c0.y, c0.z, c0.w, c1.x, c1.y, c1.z, c1.w};
#pragma unroll
        for (int j = 0; j < 8; ++j) {
            float s = sp * sigf(cs[j]);
            if (s >= FLOORV) {
                int b = (int)((s - FLOORV) * BIN_SCALE);
                if (b > NBINS - 1) b = NBINS - 1;
                if (b >= csel) {
                    int pos = atomicAdd(&count[lev], 1);
                    if (pos < CAND_CAP) cand[lev * CAND_CAP + pos] = e + j;
                }
            }
        }
    }
}

__global__ __launch_bounds__(1024) void k_final(LevelParams P, const int* cand, const int* count,
                                                const int* wptr, const int* hptr, float* out) {
    // Keys = f32 score via the step-rounded numpy chain 1/(1+exp(-x)) with CR
    // f32 exp, stored as bit pattern (positive -> monotone as ints).
    // Bit-equal keys -> ascending flat index (stable top_k tie-break).
    __shared__ int ks[CAND_CAP];
    __shared__ int si[CAND_CAP];
    const int lev = blockIdx.x;
    int n = count[lev];
    if (n > CAND_CAP) n = CAND_CAP;
    const float* __restrict__ cls = P.cls[lev];
    const float* __restrict__ pss = P.pss[lev];
    const float* __restrict__ box = P.box[lev];

    for (int i = threadIdx.x; i < CAND_CAP; i += 1024) {
        if (i < n) {
            int idx = cand[lev * CAND_CAP + i];
            float a32 = np_sigmoid_f32(cls[idx]);
            float b32 = np_sigmoid_f32(pss[idx / NUM_CLASSES]);
            float s = __fmul_rn(a32, b32);
            ks[i] = __float_as_int(s);
            si[i] = idx;
        } else {
            ks[i] = 0;            // +0.0f, below every real score key
            si[i] = 0x7fffffff;
        }
    }
    __syncthreads();

    // bitonic sort: descending by key, ties -> ascending index
    for (int k = 2; k <= CAND_CAP; k <<= 1) {
        for (int j = k >> 1; j > 0; j >>= 1) {
            for (int t = threadIdx.x; t < CAND_CAP / 2; t += 1024) {
                int i = ((t & ~(j - 1)) << 1) | (t & (j - 1));
                int ix = i | j;
                int k1 = ks[i], k2 = ks[ix];
                int i1 = si[i], i2 = si[ix];
                bool before = (k1 > k2) || (k1 == k2 && i1 < i2);
                bool dirDesc = ((i & k) == 0);
                if (before != dirDesc) {
                    ks[i] = k2; ks[ix] = k1;
                    si[i] = i2; si[ix] = i1;
                }
            }
            __syncthreads();
        }
    }

    const float w = (float)wptr[0], h = (float)hptr[0];
    const float invw = 1.0f / w, invh = 1.0f / h;
    for (int r = threadIdx.x; r < TOPK; r += 1024) {
        float s = __int_as_float(ks[r]);
        int idx = si[r];
        bool keep = (r < n) && (s > 0.05f);
        int row = lev * TOPK + r;
        float b0 = 0.f, b1 = 0.f, b2 = 0.f, b3 = 0.f;
        if (keep) {
            int a = idx / NUM_CLASSES;
            b0 = fminf(fmaxf(box[a * 4 + 0] * invw, 0.f), 1.f);
            b1 = fminf(fmaxf(box[a * 4 + 1] * invh, 0.f), 1.f);
            b2 = fminf(fmaxf(box[a * 4 + 2] * invw, 0.f), 1.f);
            b3 = fminf(fmaxf(box[a * 4 + 3] * invh, 0.f), 1.f);
        }
        out[row * 4 + 0] = b0;
        out[row * 4 + 1] = b1;
        out[row * 4 + 2] = b2;
        out[row * 4 + 3] = b3;
        out[NUM_LEVELS * TOPK * 4 + row] = keep ? s : 0.0f;
        out[NUM_LEVELS * TOPK * 5 + row] = keep ? (float)(idx % NUM_CLASSES) : -1.0f;
    }
}

extern "C" void kernel_launch(void* const* d_in, const int* in_sizes, int n_in,
                              void* d_out, int out_size, void* d_ws, size_t ws_size,
                              hipStream_t stream) {
    static const int HWS[NUM_LEVELS] = {262144, 65536, 16384, 4096, 1024};

    LevelParams P;
    int blk = 0;
    for (int i = 0; i < NUM_LEVELS; ++i) {
        P.cls[i] = (const float*)d_in[3 * i + 0];
        P.box[i] = (const float*)d_in[3 * i + 1];
        P.pss[i] = (const float*)d_in[3 * i + 2];
        P.blk_start[i] = blk;
        blk += HWS[i] * NUM_CLASSES / ELEMS_PER_BLOCK;  // all exactly divisible
    }
    P.blk_start[NUM_LEVELS] = blk;  // 3410

    const int* wp = (const int*)d_in[15];
    const int* hp = (const int*)d_in[16];

    unsigned char* ws = (unsigned char*)d_ws;
    unsigned* hist = (unsigned*)ws;                      // 5*256*4 = 5120 B
    int* cutoff = (int*)(ws + 5120);                     // 20 B
    int* count = (int*)(ws + 5140);                      // 20 B
    int* cand = (int*)(ws + 5184);                       // 5*4096*4 = 81920 B

    hipMemsetAsync(ws, 0, 5184, stream);
    k_hist<<<blk, 256, 0, stream>>>(P, hist);
    k_cutoff<<<NUM_LEVELS, 64, 0, stream>>>(hist, cutoff);
    k_compact<<<blk, 256, 0, stream>>>(P, cutoff, count, cand);
    k_final<<<NUM_LEVELS, 1024, 0, stream>>>(P, cand, count, wp, hp, (float*)d_out);
}